// Round 1
// baseline (587.821 us; speedup 1.0000x reference)
//
#include <hip/hip_runtime.h>
#include <hip/hip_bf16.h>
#include <math.h>

#define NN 1536
#define TT 10
#define DD 64
#define NHEAD 4
#define HDIM 16
#define PP 1178880   // NN*(NN-1)/2

// ws layout (float offsets)
#define WS_NODE0 0
#define WS_G1    98304
#define WS_G2    196608
#define WS_GI    294912
#define WS_GJ    491520
#define WS_W2T   688128
#define WS_TXY   696320

static __device__ __forceinline__ float dot64(const float* __restrict__ a,
                                              const float* __restrict__ b) {
    float s = 0.f;
#pragma unroll
    for (int c = 0; c < 64; c += 4) {
        float4 av = *reinterpret_cast<const float4*>(a + c);
        float4 bv = *reinterpret_cast<const float4*>(b + c);
        s = fmaf(av.x, bv.x, s);
        s = fmaf(av.y, bv.y, s);
        s = fmaf(av.z, bv.z, s);
        s = fmaf(av.w, bv.w, s);
    }
    return s;
}

// ---------------- Transformer encoder layer, one block per node ----------------
__global__ __launch_bounds__(64) void k_transformer(
    const float* __restrict__ traj,
    const float* __restrict__ wqkv, const float* __restrict__ bqkv,
    const float* __restrict__ wo,   const float* __restrict__ bo,
    const float* __restrict__ g1,   const float* __restrict__ b1,
    const float* __restrict__ fw1,  const float* __restrict__ fb1,
    const float* __restrict__ fw2,  const float* __restrict__ fb2,
    const float* __restrict__ g2,   const float* __restrict__ b2,
    float* __restrict__ node_out)
{
    __shared__ __align__(16) float xs[TT][DD];        // original x, later ln1 out
    __shared__ __align__(16) float qkvs[TT][3 * DD];
    __shared__ __align__(16) float cs[TT][DD];        // ctx, later ff1 out
    __shared__ __align__(16) float ys[TT][DD];
    __shared__ float mv[TT][2];

    const int n = blockIdx.x, tid = threadIdx.x;
    const float* xg = traj + (size_t)n * TT * DD;

    for (int idx = tid; idx < TT * DD; idx += 64)
        xs[idx / DD][idx % DD] = xg[idx];
    __syncthreads();

    // qkv = x @ Wqkv^T + b
    for (int idx = tid; idx < TT * 3 * DD; idx += 64) {
        int t = idx / (3 * DD), o = idx % (3 * DD);
        float a = bqkv[o] + dot64(&xs[t][0], wqkv + o * DD);
        qkvs[t][o] = a;
    }
    __syncthreads();

    // attention: thread = h*TT + t
    if (tid < NHEAD * TT) {
        int h = tid / TT, t = tid % TT;
        float sc[TT];
        float mx = -1e30f;
#pragma unroll
        for (int s = 0; s < TT; ++s) {
            float a = 0.f;
#pragma unroll
            for (int d = 0; d < HDIM; ++d)
                a = fmaf(qkvs[t][h * HDIM + d], qkvs[s][DD + h * HDIM + d], a);
            a *= 0.25f;   // 1/sqrt(16)
            sc[s] = a;
            mx = fmaxf(mx, a);
        }
        float den = 0.f;
#pragma unroll
        for (int s = 0; s < TT; ++s) { sc[s] = expf(sc[s] - mx); den += sc[s]; }
        float inv = 1.f / den;
#pragma unroll
        for (int d = 0; d < HDIM; ++d) {
            float a = 0.f;
#pragma unroll
            for (int s = 0; s < TT; ++s)
                a = fmaf(sc[s], qkvs[s][2 * DD + h * HDIM + d], a);
            cs[t][h * HDIM + d] = a * inv;
        }
    }
    __syncthreads();

    // out proj + residual
    for (int idx = tid; idx < TT * DD; idx += 64) {
        int t = idx / DD, o = idx % DD;
        float a = bo[o] + dot64(&cs[t][0], wo + o * DD);
        ys[t][o] = xs[t][o] + a;
    }
    __syncthreads();

    // LN1 stats
    if (tid < TT) {
        float m = 0.f;
        for (int c = 0; c < DD; ++c) m += ys[tid][c];
        m *= (1.f / DD);
        float v = 0.f;
        for (int c = 0; c < DD; ++c) { float d = ys[tid][c] - m; v = fmaf(d, d, v); }
        v *= (1.f / DD);
        mv[tid][0] = m;
        mv[tid][1] = rsqrtf(v + 1e-5f);
    }
    __syncthreads();
    for (int idx = tid; idx < TT * DD; idx += 64) {
        int t = idx / DD, o = idx % DD;
        xs[t][o] = (ys[t][o] - mv[t][0]) * mv[t][1] * g1[o] + b1[o];
    }
    __syncthreads();

    // FF1 (relu)
    for (int idx = tid; idx < TT * DD; idx += 64) {
        int t = idx / DD, p = idx % DD;
        float a = fb1[p] + dot64(&xs[t][0], fw1 + p * DD);
        cs[t][p] = fmaxf(a, 0.f);
    }
    __syncthreads();

    // FF2 + residual
    for (int idx = tid; idx < TT * DD; idx += 64) {
        int t = idx / DD, o = idx % DD;
        float a = fb2[o] + dot64(&cs[t][0], fw2 + o * DD);
        ys[t][o] = xs[t][o] + a;
    }
    __syncthreads();

    // LN2 stats
    if (tid < TT) {
        float m = 0.f;
        for (int c = 0; c < DD; ++c) m += ys[tid][c];
        m *= (1.f / DD);
        float v = 0.f;
        for (int c = 0; c < DD; ++c) { float d = ys[tid][c] - m; v = fmaf(d, d, v); }
        v *= (1.f / DD);
        mv[tid][0] = m;
        mv[tid][1] = rsqrtf(v + 1e-5f);
    }
    __syncthreads();

    // node = mean_t LN2(t, o) ; mean(g*z+b) = g*mean(z)+b
    if (tid < DD) {
        float acc = 0.f;
#pragma unroll
        for (int t = 0; t < TT; ++t)
            acc += (ys[t][tid] - mv[t][0]) * mv[t][1];
        node_out[n * DD + tid] = acc * g2[tid] * (1.f / TT) + b2[tid];
    }
}

// ---------------- GCN layer: Y = relu((A @ X) @ W^T + b) ----------------
// block = 128 threads: 4 rows x 32 channel-pairs
__global__ __launch_bounds__(128) void k_gcn(
    const float* __restrict__ A, const float* __restrict__ X,
    const float* __restrict__ W, const float* __restrict__ b,
    float* __restrict__ Y)
{
    __shared__ __align__(16) float Xs[128][64];
    __shared__ float As[4][128];
    __shared__ __align__(16) float yrow[4][68];

    const int tid = threadIdx.x;
    const int r = tid >> 5;          // 0..3
    const int cp = tid & 31;         // channel pair: c = 2*cp
    const int i0 = blockIdx.x * 4;

    float acc0 = 0.f, acc1 = 0.f;
    for (int j0 = 0; j0 < NN; j0 += 128) {
        for (int idx = tid; idx < 128 * 64; idx += 128) {
            int j = idx >> 6, c = idx & 63;
            Xs[j][c] = X[(size_t)(j0 + j) * 64 + c];
        }
        for (int idx = tid; idx < 4 * 128; idx += 128) {
            int rr = idx >> 7, j = idx & 127;
            As[rr][j] = A[(size_t)(i0 + rr) * NN + j0 + j];
        }
        __syncthreads();
#pragma unroll 8
        for (int j = 0; j < 128; ++j) {
            float2 xv = *reinterpret_cast<const float2*>(&Xs[j][2 * cp]);
            float av = As[r][j];
            acc0 = fmaf(av, xv.x, acc0);
            acc1 = fmaf(av, xv.y, acc1);
        }
        __syncthreads();
    }
    yrow[r][2 * cp] = acc0;
    yrow[r][2 * cp + 1] = acc1;
    __syncthreads();

    // W multiply: each thread does 2 outputs for its row
#pragma unroll
    for (int k = 0; k < 2; ++k) {
        int o = 2 * cp + k;
        float z = b[o] + dot64(&yrow[r][0], W + o * 64);
        Y[(size_t)(i0 + r) * 64 + o] = fmaxf(z, 0.f);
    }
}

// ---------------- prep: gi/gj tables, W2 transpose, traj xy extraction ----------------
__global__ __launch_bounds__(256) void k_prep(
    const float* __restrict__ node, const float* __restrict__ e_w1,
    const float* __restrict__ e_w2, const float* __restrict__ traj,
    float* __restrict__ gi_t, float* __restrict__ gj_t,
    float* __restrict__ w2t, float* __restrict__ txy)
{
    const int b = blockIdx.x;
    if (b < NN) {
        __shared__ __align__(16) float ns[64];
        if (threadIdx.x < 64) ns[threadIdx.x] = node[b * 64 + threadIdx.x];
        __syncthreads();
        int o = threadIdx.x;
        if (o < 128) {
            gi_t[b * 128 + o] = dot64(ns, e_w1 + o * 138);
        } else {
            int o2 = o - 128;
            gj_t[b * 128 + o2] = dot64(ns, e_w1 + o2 * 138 + 64);
        }
    } else if (b == NN) {
        for (int idx = threadIdx.x; idx < 128 * 64; idx += 256) {
            int o = idx >> 6, m = idx & 63;
            w2t[idx] = e_w2[m * 128 + o];
        }
    } else {
        // 8 blocks stride over txy extraction
        for (int idx = (b - (NN + 1)) * 256 + threadIdx.x; idx < NN * 20; idx += 8 * 256) {
            int n2 = idx / 20, rr = idx % 20, t = rr >> 1, c = rr & 1;
            txy[idx] = traj[((size_t)n2 * TT + t) * DD + c];
        }
    }
}

// ---------------- edge predictor: one thread per pair ----------------
__global__ __launch_bounds__(256) void k_edge(
    const float* __restrict__ txy,
    const float* __restrict__ gi_t, const float* __restrict__ gj_t,
    const float* __restrict__ e_w1, const float* __restrict__ e_b1,
    const float* __restrict__ w2t,  const float* __restrict__ e_b2,
    const float* __restrict__ e_w3, const float* __restrict__ e_b3,
    float* __restrict__ out)
{
    const int i = blockIdx.x;
    const int j = i + 1 + blockIdx.y * 256 + threadIdx.x;
    if (j >= NN) return;
    const int p = i * (NN - 1) - (i * (i - 1)) / 2 + (j - i - 1);

    // distances / hist
    const float* ti = txy + i * 20;   // uniform per block -> scalar loads
    const float* tj = txy + j * 20;
    float hist[10];
    float dmin = 3.4e38f;
#pragma unroll
    for (int t = 0; t < 10; ++t) {
        float2 a = *reinterpret_cast<const float2*>(ti + 2 * t);
        float2 bb = *reinterpret_cast<const float2*>(tj + 2 * t);
        float dx = a.x - bb.x, dy = a.y - bb.y;
        float d = sqrtf(fmaf(dx, dx, dy * dy));
        dmin = fminf(dmin, d);
        hist[t] = 1.f / (1.f + expf(50.f - 10.f * d));
    }

    // MLP: layer1 (via gi/gj tables + hist part), stream into layer2 accumulators
    float h2[64];
#pragma unroll
    for (int m = 0; m < 64; ++m) h2[m] = e_b2[m];

    const float* gi_row = gi_t + i * 128;          // uniform
    const float* gj_row = gj_t + (size_t)j * 128;  // per-thread

#pragma unroll 4
    for (int o = 0; o < 128; ++o) {
        float a = e_b1[o] + gi_row[o] + gj_row[o];
        const float* wh = e_w1 + o * 138 + 128;    // uniform
#pragma unroll
        for (int t = 0; t < 10; ++t) a = fmaf(hist[t], wh[t], a);
        a = fmaxf(a, 0.f);
        const float* w2 = w2t + o * 64;            // uniform
#pragma unroll
        for (int m = 0; m < 64; ++m) h2[m] = fmaf(a, w2[m], h2[m]);
    }

    float z = e_b3[0];
#pragma unroll
    for (int m = 0; m < 64; ++m) z = fmaf(fmaxf(h2[m], 0.f), e_w3[m], z);
    float prob = 1.f / (1.f + expf(-z));

    out[p] = prob;
    out[PP + p] = dmin;
    float* hp = out + 2 * (size_t)PP + (size_t)p * 10;
#pragma unroll
    for (int t = 0; t < 10; ++t) hp[t] = hist[t];
}

extern "C" void kernel_launch(void* const* d_in, const int* in_sizes, int n_in,
                              void* d_out, int out_size, void* d_ws, size_t ws_size,
                              hipStream_t stream) {
    const float* traj   = (const float*)d_in[0];
    const float* adj    = (const float*)d_in[1];
    const float* w_in   = (const float*)d_in[2];
    const float* b_in   = (const float*)d_in[3];
    const float* w_out  = (const float*)d_in[4];
    const float* b_out  = (const float*)d_in[5];
    const float* ln1g   = (const float*)d_in[6];
    const float* ln1b   = (const float*)d_in[7];
    const float* fw1    = (const float*)d_in[8];
    const float* fb1    = (const float*)d_in[9];
    const float* fw2    = (const float*)d_in[10];
    const float* fb2    = (const float*)d_in[11];
    const float* ln2g   = (const float*)d_in[12];
    const float* ln2b   = (const float*)d_in[13];
    const float* gcn_w  = (const float*)d_in[14];
    const float* gcn_b  = (const float*)d_in[15];
    const float* e_w1   = (const float*)d_in[16];
    const float* e_b1   = (const float*)d_in[17];
    const float* e_w2   = (const float*)d_in[18];
    const float* e_b2   = (const float*)d_in[19];
    const float* e_w3   = (const float*)d_in[20];
    const float* e_b3   = (const float*)d_in[21];

    float* ws    = (float*)d_ws;
    float* node0 = ws + WS_NODE0;
    float* g1b   = ws + WS_G1;
    float* g2b   = ws + WS_G2;
    float* gi    = ws + WS_GI;
    float* gj    = ws + WS_GJ;
    float* w2t   = ws + WS_W2T;
    float* txy   = ws + WS_TXY;

    k_transformer<<<NN, 64, 0, stream>>>(traj, w_in, b_in, w_out, b_out,
                                         ln1g, ln1b, fw1, fb1, fw2, fb2,
                                         ln2g, ln2b, node0);

    k_gcn<<<NN / 4, 128, 0, stream>>>(adj, node0, gcn_w,        gcn_b,       g1b);
    k_gcn<<<NN / 4, 128, 0, stream>>>(adj, g1b,   gcn_w + 4096, gcn_b + 64,  g2b);
    k_gcn<<<NN / 4, 128, 0, stream>>>(adj, g2b,   gcn_w + 8192, gcn_b + 128, g1b);

    k_prep<<<NN + 9, 256, 0, stream>>>(g1b, e_w1, e_w2, traj, gi, gj, w2t, txy);

    dim3 egrid(NN - 1, 6);
    k_edge<<<egrid, 256, 0, stream>>>(txy, gi, gj, e_w1, e_b1, w2t, e_b2,
                                      e_w3, e_b3, (float*)d_out);
}